// Round 1
// baseline (65.519 us; speedup 1.0000x reference)
//
#include <hip/hip_runtime.h>

// VocabParallelEmbeddingWithLoRA: embedding gather + rank-16 LoRA combine.
// out[t, d] = base_weight[base_idx(t), d] + sum_r a[t,r] * lora_b[li[t], d, r]
// where a[t,:] = lora_a[li[t], x[t], :],
//       base_idx(t) = x[t] + (x[t] >= ORG_VOCAB ? li[t]*EXTRA : 0)

constexpr int ORG_VOCAB = 32000;
constexpr int EXTRA     = 256;
constexpr int RANK      = 16;
constexpr int D         = 2048;

__global__ __launch_bounds__(256) void lora_embed_kernel(
    const int*   __restrict__ x,        // [T] token ids
    const int*   __restrict__ li,       // [T] lora indices
    const float* __restrict__ base_w,   // [ORG_VOCAB + MAX_LORAS*EXTRA, D]
    const float* __restrict__ lora_a,   // [MAX_LORAS, ORG_VOCAB+EXTRA, RANK]
    const float* __restrict__ lora_b,   // [MAX_LORAS, D, RANK]
    float*       __restrict__ out)      // [T, D]
{
    const int t   = blockIdx.x;
    const int tok = x[t];
    const int l   = li[t];

    // a-vector: 16 floats, identical address for all lanes -> broadcast load.
    const float* __restrict__ ap =
        lora_a + ((size_t)l * (ORG_VOCAB + EXTRA) + (size_t)tok) * RANK;
    const float4 a0 = *(const float4*)(ap + 0);
    const float4 a1 = *(const float4*)(ap + 4);
    const float4 a2 = *(const float4*)(ap + 8);
    const float4 a3 = *(const float4*)(ap + 12);

    const size_t base_idx = (size_t)tok + (tok >= ORG_VOCAB ? (size_t)(l * EXTRA) : (size_t)0);
    const float* __restrict__ brow = base_w + base_idx * (size_t)D;
    const float* __restrict__ bl   = lora_b + (size_t)l * (size_t)(D * RANK);
    float* __restrict__ orow       = out + (size_t)t * (size_t)D;

    // 256 threads x float4 = 1024 floats per sweep; 2 sweeps cover D=2048.
    for (int d4 = threadIdx.x; d4 < D / 4; d4 += 256) {
        const int d0 = d4 * 4;
        const float4 base4 = *(const float4*)(brow + d0);
        float r[4] = {base4.x, base4.y, base4.z, base4.w};
        #pragma unroll
        for (int j = 0; j < 4; ++j) {
            const float4* __restrict__ bp = (const float4*)(bl + (size_t)(d0 + j) * RANK);
            const float4 b0 = bp[0];
            const float4 b1 = bp[1];
            const float4 b2 = bp[2];
            const float4 b3 = bp[3];
            r[j] += a0.x * b0.x + a0.y * b0.y + a0.z * b0.z + a0.w * b0.w
                  + a1.x * b1.x + a1.y * b1.y + a1.z * b1.z + a1.w * b1.w
                  + a2.x * b2.x + a2.y * b2.y + a2.z * b2.z + a2.w * b2.w
                  + a3.x * b3.x + a3.y * b3.y + a3.z * b3.z + a3.w * b3.w;
        }
        *(float4*)(orow + d0) = make_float4(r[0], r[1], r[2], r[3]);
    }
}

extern "C" void kernel_launch(void* const* d_in, const int* in_sizes, int n_in,
                              void* d_out, int out_size, void* d_ws, size_t ws_size,
                              hipStream_t stream) {
    const int*   x      = (const int*)d_in[0];
    const int*   li     = (const int*)d_in[1];
    const float* base_w = (const float*)d_in[2];
    const float* lora_a = (const float*)d_in[3];
    const float* lora_b = (const float*)d_in[4];
    float*       out    = (float*)d_out;

    const int T = in_sizes[0];  // B*S = 4096
    lora_embed_kernel<<<T, 256, 0, stream>>>(x, li, base_w, lora_a, lora_b, out);
}

// Round 2
// 51.940 us; speedup vs baseline: 1.2614x; 1.2614x over previous
//
#include <hip/hip_runtime.h>

// VocabParallelEmbeddingWithLoRA, bucketed by lora index.
// out[t, d] = base_weight[base_idx(t), d] + sum_r a[t,r] * lora_b[li[t], d, r]
//   a[t,:]     = lora_a[li[t], x[t], :]
//   base_idx(t)= x[t] + (x[t] >= ORG_VOCAB ? li[t]*EXTRA : 0)
//
// Pipeline: zero meta -> count per-lora (wave-aggregated atomics) -> prefix
// -> scatter token positions into per-lora compact buckets -> main kernel.
// Main kernel: block = (group of up to G same-lora tokens) x (half of D).
// lora_b slice for the block's 1024 d-columns lives in registers (64 floats)
// and is reused across all G tokens -> 8x less lora_b traffic than per-token.

constexpr int ORG_VOCAB = 32000;
constexpr int EXTRA     = 256;
constexpr int RANK      = 16;
constexpr int D         = 2048;
constexpr int NLORA     = 8;
constexpr int G         = 8;     // tokens per main block

// meta layout (ints): [0..8) counts, [8..16) cursors, [16..24) offsets
__global__ void zero_meta_k(int* meta) {
    if (threadIdx.x < 24) meta[threadIdx.x] = 0;
}

__global__ void count_k(const int* __restrict__ li, int* __restrict__ meta, int T) {
    const int t = blockIdx.x * blockDim.x + threadIdx.x;
    const int l = (t < T) ? li[t] : -1;
    const int lane = threadIdx.x & 63;
    #pragma unroll
    for (int ll = 0; ll < NLORA; ++ll) {
        unsigned long long m = __ballot(l == ll);
        if (m != 0ull && lane == (__ffsll((long long)m) - 1))
            atomicAdd(&meta[ll], __popcll(m));
    }
}

__global__ void prefix_k(int* meta) {
    if (threadIdx.x == 0) {
        int s = 0;
        #pragma unroll
        for (int l = 0; l < NLORA; ++l) {
            meta[8 + l]  = s;   // cursor (will be bumped by scatter)
            meta[16 + l] = s;   // stable offset for main kernel
            s += meta[l];
        }
    }
}

__global__ void scatter_k(const int* __restrict__ li, int* __restrict__ meta,
                          int* __restrict__ bucket, int T) {
    const int t = blockIdx.x * blockDim.x + threadIdx.x;
    const int l = (t < T) ? li[t] : -1;
    const int lane = threadIdx.x & 63;
    #pragma unroll
    for (int ll = 0; ll < NLORA; ++ll) {
        unsigned long long m = __ballot(l == ll);
        if (m == 0ull) continue;
        const int leader = __ffsll((long long)m) - 1;
        int base = 0;
        if (lane == leader) base = atomicAdd(&meta[8 + ll], __popcll(m));
        base = __shfl(base, leader, 64);
        if (l == ll) {
            const int pos = base + __popcll(m & ((1ull << lane) - 1ull));
            bucket[pos] = t;
        }
    }
}

__global__ __launch_bounds__(256) void lora_main_k(
    const int*   __restrict__ x,        // [T] token ids
    const int*   __restrict__ bucket,   // [T] compact token positions by lora
    const int*   __restrict__ meta,     // counts/cursors/offsets
    const float* __restrict__ base_w,   // [ORG_VOCAB + NLORA*EXTRA, D]
    const float* __restrict__ lora_a,   // [NLORA, ORG_VOCAB+EXTRA, RANK]
    const float* __restrict__ lora_b,   // [NLORA, D, RANK]
    float*       __restrict__ out)      // [T, D]
{
    const int l     = blockIdx.y;
    const int cnt   = meta[l];
    const int start = blockIdx.x * G;
    if (start >= cnt) return;
    const int n    = min(G, cnt - start);
    const int offs = meta[16 + l];
    const int d0   = blockIdx.z * (D / 2) + threadIdx.x * 4;  // 4 d-rows per thread

    // lora_b slice for this thread's 4 d-rows: 4 rows x 16 rank = 16 float4.
    float4 breg[4][4];
    const float* __restrict__ bl = lora_b + (size_t)l * (size_t)(D * RANK);
    #pragma unroll
    for (int j = 0; j < 4; ++j)
        #pragma unroll
        for (int q = 0; q < 4; ++q)
            breg[j][q] = *(const float4*)(bl + (size_t)(d0 + j) * RANK + q * 4);

    __shared__ int   s_tok[G];        // flat token position t
    __shared__ int   s_bidx[G];       // base_weight row
    __shared__ float s_a[G][RANK];    // a-vectors

    if (threadIdx.x < n) {
        const int t   = bucket[offs + start + threadIdx.x];
        const int tok = x[t];
        s_tok[threadIdx.x]  = t;
        s_bidx[threadIdx.x] = tok + (tok >= ORG_VOCAB ? l * EXTRA : 0);
    }
    __syncthreads();
    if (threadIdx.x < n * RANK) {
        const int i = threadIdx.x >> 4;
        const int r = threadIdx.x & 15;
        const int tok = x[s_tok[i]];
        s_a[i][r] = lora_a[((size_t)l * (ORG_VOCAB + EXTRA) + (size_t)tok) * RANK + r];
    }
    __syncthreads();

    for (int i = 0; i < n; ++i) {
        const float4 base4 = *(const float4*)(base_w + (size_t)s_bidx[i] * D + d0);
        float4 acc = base4;
        #pragma unroll
        for (int q = 0; q < 4; ++q) {
            const float4 aq = *(const float4*)(&s_a[i][q * 4]);
            acc.x += aq.x * breg[0][q].x + aq.y * breg[0][q].y + aq.z * breg[0][q].z + aq.w * breg[0][q].w;
            acc.y += aq.x * breg[1][q].x + aq.y * breg[1][q].y + aq.z * breg[1][q].z + aq.w * breg[1][q].w;
            acc.z += aq.x * breg[2][q].x + aq.y * breg[2][q].y + aq.z * breg[2][q].z + aq.w * breg[2][q].w;
            acc.w += aq.x * breg[3][q].x + aq.y * breg[3][q].y + aq.z * breg[3][q].z + aq.w * breg[3][q].w;
        }
        *(float4*)(out + (size_t)s_tok[i] * D + d0) = acc;
    }
}

extern "C" void kernel_launch(void* const* d_in, const int* in_sizes, int n_in,
                              void* d_out, int out_size, void* d_ws, size_t ws_size,
                              hipStream_t stream) {
    const int*   x      = (const int*)d_in[0];
    const int*   li     = (const int*)d_in[1];
    const float* base_w = (const float*)d_in[2];
    const float* lora_a = (const float*)d_in[3];
    const float* lora_b = (const float*)d_in[4];
    float*       out    = (float*)d_out;

    const int T = in_sizes[0];  // B*S = 4096

    int* meta   = (int*)d_ws;             // 24 ints
    int* bucket = (int*)d_ws + 32;        // T ints

    const int nb = (T + 255) / 256;
    zero_meta_k<<<1, 64, 0, stream>>>(meta);
    count_k<<<nb, 256, 0, stream>>>(li, meta, T);
    prefix_k<<<1, 64, 0, stream>>>(meta);
    scatter_k<<<nb, 256, 0, stream>>>(li, meta, bucket, T);

    dim3 grid((T + G - 1) / G, NLORA, 2);
    lora_main_k<<<grid, 256, 0, stream>>>(x, bucket, meta, base_w, lora_a, lora_b, out);
}

// Round 3
// 38.930 us; speedup vs baseline: 1.6830x; 1.3342x over previous
//
#include <hip/hip_runtime.h>

// VocabParallelEmbeddingWithLoRA, bucketed by lora index — 2-kernel pipeline.
// out[t, d] = base_weight[base_idx(t), d] + sum_r a[t,r] * lora_b[li[t], d, r]
//   a[t,:]      = lora_a[li[t], x[t], :]
//   base_idx(t) = x[t] + (x[t] >= ORG_VOCAB ? li[t]*EXTRA : 0)
//
// K1 (single block, 1024 thr): count per-lora -> prefix (pad buckets to G=8)
//   -> group->lora map -> scatter token ids into compact padded buckets.
// K2 (dense grid of (T/G + NLORA) x 2 blocks): each block = 8 same-lora
//   tokens x half of D; lora_b slice (64 floats) in registers, reused 8x.

constexpr int ORG_VOCAB = 32000;
constexpr int EXTRA     = 256;
constexpr int RANK      = 16;
constexpr int D         = 2048;
constexpr int NLORA     = 8;
constexpr int G         = 8;       // tokens per main block
constexpr int BK_T      = 1024;    // bucketize block size

// meta ints: [16..24) aligned slot offsets, [24..32) group offsets, [40] total groups
__global__ __launch_bounds__(BK_T) void bucketize_k(
    const int* __restrict__ li, int* __restrict__ meta,
    int* __restrict__ bucket, int* __restrict__ glora, int T)
{
    __shared__ int cnt[NLORA], cur[NLORA], soff[NLORA + 1], sgoff[NLORA + 1];
    const int tid  = threadIdx.x;
    const int lane = tid & 63;
    if (tid < NLORA) cnt[tid] = 0;
    __syncthreads();

    // count (wave-aggregated LDS atomics)
    for (int t = tid; t < T; t += BK_T) {
        const int l = li[t];
        #pragma unroll
        for (int ll = 0; ll < NLORA; ++ll) {
            unsigned long long m = __ballot(l == ll);
            if (m != 0ull && lane == (__ffsll((long long)m) - 1))
                atomicAdd(&cnt[ll], __popcll(m));
        }
    }
    __syncthreads();

    // prefix with padding to multiples of G
    if (tid == 0) {
        int s = 0, gs = 0;
        for (int l = 0; l < NLORA; ++l) {
            soff[l] = s; sgoff[l] = gs; cur[l] = s;
            const int ng = (cnt[l] + G - 1) / G;
            s += ng * G; gs += ng;
        }
        soff[NLORA] = s; sgoff[NLORA] = gs;
        #pragma unroll
        for (int l = 0; l < NLORA; ++l) { meta[16 + l] = soff[l]; meta[24 + l] = sgoff[l]; }
        meta[40] = gs;
    }
    __syncthreads();

    const int totalSlots  = soff[NLORA];
    const int totalGroups = sgoff[NLORA];
    // sentinel-init padded slots (scatter overwrites real ones after barrier)
    for (int i = tid; i < totalSlots; i += BK_T) bucket[i] = -1;
    // group -> lora map
    for (int g = tid; g < totalGroups; g += BK_T) {
        int l = 0;
        while (g >= sgoff[l + 1]) ++l;
        glora[g] = l;
    }
    __syncthreads();

    // scatter (wave-aggregated; intra-bucket order irrelevant)
    for (int t = tid; t < T; t += BK_T) {
        const int l = li[t];
        #pragma unroll
        for (int ll = 0; ll < NLORA; ++ll) {
            unsigned long long m = __ballot(l == ll);
            if (m == 0ull) continue;
            const int leader = __ffsll((long long)m) - 1;
            int base = 0;
            if (lane == leader) base = atomicAdd(&cur[ll], __popcll(m));
            base = __shfl(base, leader, 64);
            if (l == ll)
                bucket[base + __popcll(m & ((1ull << lane) - 1ull))] = t;
        }
    }
}

__global__ __launch_bounds__(256) void lora_main_k(
    const int*   __restrict__ x,        // [T] token ids
    const int*   __restrict__ bucket,   // padded compact token positions
    const int*   __restrict__ glora,    // [totalGroups] group -> lora
    const int*   __restrict__ meta,
    const float* __restrict__ base_w,   // [ORG_VOCAB + NLORA*EXTRA, D]
    const float* __restrict__ lora_a,   // [NLORA, ORG_VOCAB+EXTRA, RANK]
    const float* __restrict__ lora_b,   // [NLORA, D, RANK]
    float*       __restrict__ out)      // [T, D]
{
    const int g = blockIdx.x;
    if (g >= meta[40]) return;
    const int l     = glora[g];
    const int slot0 = meta[16 + l] + (g - meta[24 + l]) * G;
    const int d0    = blockIdx.y * (D / 2) + threadIdx.x * 4;

    // lora_b slice for this thread's 4 d-rows: 16 float4, reused for 8 tokens.
    float4 breg[4][4];
    const float* __restrict__ bl = lora_b + (size_t)l * (size_t)(D * RANK);
    #pragma unroll
    for (int j = 0; j < 4; ++j)
        #pragma unroll
        for (int q = 0; q < 4; ++q)
            breg[j][q] = *(const float4*)(bl + (size_t)(d0 + j) * RANK + q * 4);

    __shared__ int   s_t[G];          // flat token position (or -1 pad)
    __shared__ int   s_bidx[G];       // base_weight row
    __shared__ float s_a[G][RANK];    // a-vectors

    if (threadIdx.x < G) {
        const int t   = bucket[slot0 + threadIdx.x];
        s_t[threadIdx.x] = t;
        const int tok = (t >= 0) ? x[t] : 0;
        s_bidx[threadIdx.x] = tok + (tok >= ORG_VOCAB ? l * EXTRA : 0);
        // stash token id for the a-gather phase
        s_a[threadIdx.x][0] = __int_as_float(tok);
    }
    __syncthreads();
    int tokid[1];
    if (threadIdx.x < G * RANK) tokid[0] = __float_as_int(s_a[threadIdx.x >> 4][0]);
    __syncthreads();
    if (threadIdx.x < G * RANK) {
        const int i = threadIdx.x >> 4;
        const int r = threadIdx.x & 15;
        s_a[i][r] = (s_t[i] >= 0)
            ? lora_a[((size_t)l * (ORG_VOCAB + EXTRA) + (size_t)tokid[0]) * RANK + r]
            : 0.0f;
    }
    __syncthreads();

    #pragma unroll
    for (int i = 0; i < G; ++i) {
        const int t = s_t[i];               // uniform across block
        if (t < 0) continue;
        const float4 base4 = *(const float4*)(base_w + (size_t)s_bidx[i] * D + d0);
        float4 acc = base4;
        #pragma unroll
        for (int q = 0; q < 4; ++q) {
            const float4 aq = *(const float4*)(&s_a[i][q * 4]);
            acc.x += aq.x * breg[0][q].x + aq.y * breg[0][q].y + aq.z * breg[0][q].z + aq.w * breg[0][q].w;
            acc.y += aq.x * breg[1][q].x + aq.y * breg[1][q].y + aq.z * breg[1][q].z + aq.w * breg[1][q].w;
            acc.z += aq.x * breg[2][q].x + aq.y * breg[2][q].y + aq.z * breg[2][q].z + aq.w * breg[2][q].w;
            acc.w += aq.x * breg[3][q].x + aq.y * breg[3][q].y + aq.z * breg[3][q].z + aq.w * breg[3][q].w;
        }
        *(float4*)(out + (size_t)t * D + d0) = acc;
    }
}

extern "C" void kernel_launch(void* const* d_in, const int* in_sizes, int n_in,
                              void* d_out, int out_size, void* d_ws, size_t ws_size,
                              hipStream_t stream) {
    const int*   x      = (const int*)d_in[0];
    const int*   li     = (const int*)d_in[1];
    const float* base_w = (const float*)d_in[2];
    const float* lora_a = (const float*)d_in[3];
    const float* lora_b = (const float*)d_in[4];
    float*       out    = (float*)d_out;

    const int T = in_sizes[0];  // B*S = 4096

    int* meta   = (int*)d_ws;                       // 64 ints
    int* bucket = (int*)d_ws + 64;                  // T + NLORA*G ints (padded)
    int* glora  = bucket + T + NLORA * G;           // T/G + NLORA ints

    bucketize_k<<<1, BK_T, 0, stream>>>(li, meta, bucket, glora, T);

    const int maxGroups = T / G + NLORA;            // upper bound, real count in meta[40]
    dim3 grid(maxGroups, 2);
    lora_main_k<<<grid, 256, 0, stream>>>(x, bucket, glora, meta, base_w, lora_a, lora_b, out);
}

// Round 4
// 34.115 us; speedup vs baseline: 1.9206x; 1.1412x over previous
//
#include <hip/hip_runtime.h>

// VocabParallelEmbeddingWithLoRA — bucketed + transposed-B, 2-kernel pipeline.
// out[t, d] = base_weight[base_idx(t), d] + sum_r a[t,r] * lora_b[li[t], d, r]
//   a[t,:]      = lora_a[li[t], x[t], :]
//   base_idx(t) = x[t] + (x[t] >= ORG_VOCAB ? li[t]*EXTRA : 0)
//
// K1 (65 blocks x 1024 thr):
//   block 0      : bucketize (count -> prefix pad-to-G -> group map -> scatter)
//   blocks 1..64 : transpose lora_b [l][d][r] -> bT [l][r][d] (coalesced writes)
// K2 (dense grid (T/G + NLORA) x 2): block = 16 same-lora tokens x 1024 d.
//   Thread owns 4 consecutive d; bT register tile loaded via 16 fully
//   coalesced float4 loads (no line amplification), reused for 16 tokens.

constexpr int ORG_VOCAB = 32000;
constexpr int EXTRA     = 256;
constexpr int RANK      = 16;
constexpr int D         = 2048;
constexpr int NLORA     = 8;
constexpr int G         = 16;      // tokens per main block
constexpr int BK_T      = 1024;    // k1 block size

// meta ints: [16..24) slot offsets, [24..32) group offsets, [40] total groups
__global__ __launch_bounds__(BK_T) void prep_k(
    const int*   __restrict__ li,
    const float* __restrict__ lora_b,   // [NLORA, D, RANK]
    int*   __restrict__ meta,
    int*   __restrict__ bucket,
    int*   __restrict__ glora,
    float* __restrict__ bT,             // [NLORA, RANK, D]
    int T)
{
    if (blockIdx.x != 0) {
        // ---- transpose slice: one float4 of bT per thread ----
        const int o4  = (blockIdx.x - 1) * BK_T + threadIdx.x;  // < 65536
        const int l   = o4 >> 13;           // RANK*D/4 = 8192 f4 per lora
        const int rem = o4 & 8191;
        const int r   = rem >> 9;           // D/4 = 512 f4 per rank-row
        const int d4  = rem & 511;
        const float* __restrict__ src = lora_b + ((size_t)(l * D + d4 * 4) * RANK + r);
        float4 v;
        v.x = src[0 * RANK];
        v.y = src[1 * RANK];
        v.z = src[2 * RANK];
        v.w = src[3 * RANK];
        ((float4*)bT)[o4] = v;
        return;
    }

    // ---- bucketize ----
    __shared__ int cnt[NLORA], cur[NLORA], soff[NLORA + 1], sgoff[NLORA + 1];
    const int tid  = threadIdx.x;
    const int lane = tid & 63;
    if (tid < NLORA) cnt[tid] = 0;
    __syncthreads();

    for (int t = tid; t < T; t += BK_T) {
        const int l = li[t];
        #pragma unroll
        for (int ll = 0; ll < NLORA; ++ll) {
            unsigned long long m = __ballot(l == ll);
            if (m != 0ull && lane == (__ffsll((long long)m) - 1))
                atomicAdd(&cnt[ll], __popcll(m));
        }
    }
    __syncthreads();

    if (tid == 0) {
        int s = 0, gs = 0;
        for (int l = 0; l < NLORA; ++l) {
            soff[l] = s; sgoff[l] = gs; cur[l] = s;
            const int ng = (cnt[l] + G - 1) / G;
            s += ng * G; gs += ng;
        }
        soff[NLORA] = s; sgoff[NLORA] = gs;
        #pragma unroll
        for (int l = 0; l < NLORA; ++l) { meta[16 + l] = soff[l]; meta[24 + l] = sgoff[l]; }
        meta[40] = gs;
    }
    __syncthreads();

    const int totalSlots  = soff[NLORA];
    const int totalGroups = sgoff[NLORA];
    for (int i = tid; i < totalSlots; i += BK_T) bucket[i] = -1;
    for (int g = tid; g < totalGroups; g += BK_T) {
        int l = 0;
        while (g >= sgoff[l + 1]) ++l;
        glora[g] = l;
    }
    __syncthreads();

    for (int t = tid; t < T; t += BK_T) {
        const int l = li[t];
        #pragma unroll
        for (int ll = 0; ll < NLORA; ++ll) {
            unsigned long long m = __ballot(l == ll);
            if (m == 0ull) continue;
            const int leader = __ffsll((long long)m) - 1;
            int base = 0;
            if (lane == leader) base = atomicAdd(&cur[ll], __popcll(m));
            base = __shfl(base, leader, 64);
            if (l == ll)
                bucket[base + __popcll(m & ((1ull << lane) - 1ull))] = t;
        }
    }
}

__global__ __launch_bounds__(256, 2) void lora_main_k(
    const int*   __restrict__ x,        // [T] token ids
    const int*   __restrict__ bucket,   // padded compact token positions
    const int*   __restrict__ glora,    // group -> lora
    const int*   __restrict__ meta,
    const float* __restrict__ base_w,   // [ORG_VOCAB + NLORA*EXTRA, D]
    const float* __restrict__ lora_a,   // [NLORA, ORG_VOCAB+EXTRA, RANK]
    const float* __restrict__ bT,       // [NLORA, RANK, D]
    float*       __restrict__ out)      // [T, D]
{
    const int g = blockIdx.x;
    if (g >= meta[40]) return;
    const int l     = glora[g];
    const int slot0 = meta[16 + l] + (g - meta[24 + l]) * G;
    const int d0    = blockIdx.y * (D / 2) + threadIdx.x * 4;

    // Register tile: bt[r] = bT[l][r][d0..d0+3] — coalesced float4 loads.
    float4 bt[RANK];
    const float* __restrict__ btl = bT + (size_t)l * (size_t)(RANK * D);
    #pragma unroll
    for (int r = 0; r < RANK; ++r)
        bt[r] = *(const float4*)(btl + (size_t)r * D + d0);

    __shared__ int   s_t[G];          // flat token position (or -1 pad)
    __shared__ int   s_tok[G];        // token id
    __shared__ int   s_bidx[G];       // base_weight row
    __shared__ float s_a[G][RANK];    // a-vectors

    if (threadIdx.x < G) {
        const int t   = bucket[slot0 + threadIdx.x];
        s_t[threadIdx.x] = t;
        const int tok = (t >= 0) ? x[t] : 0;
        s_tok[threadIdx.x]  = tok;
        s_bidx[threadIdx.x] = tok + (tok >= ORG_VOCAB ? l * EXTRA : 0);
    }
    __syncthreads();
    {
        const int i = threadIdx.x >> 4;      // G*RANK == 256 == blockDim
        const int r = threadIdx.x & 15;
        s_a[i][r] = (s_t[i] >= 0)
            ? lora_a[((size_t)l * (ORG_VOCAB + EXTRA) + (size_t)s_tok[i]) * RANK + r]
            : 0.0f;
    }
    __syncthreads();

    #pragma unroll
    for (int i = 0; i < G; ++i) {
        const int t = s_t[i];               // uniform across block
        if (t < 0) continue;
        const float4 base4 = *(const float4*)(base_w + (size_t)s_bidx[i] * D + d0);
        float4 acc = base4;
        #pragma unroll
        for (int q = 0; q < 4; ++q) {
            const float4 aq = *(const float4*)(&s_a[i][q * 4]);
            acc.x += aq.x * bt[q*4+0].x + aq.y * bt[q*4+1].x + aq.z * bt[q*4+2].x + aq.w * bt[q*4+3].x;
            acc.y += aq.x * bt[q*4+0].y + aq.y * bt[q*4+1].y + aq.z * bt[q*4+2].y + aq.w * bt[q*4+3].y;
            acc.z += aq.x * bt[q*4+0].z + aq.y * bt[q*4+1].z + aq.z * bt[q*4+2].z + aq.w * bt[q*4+3].z;
            acc.w += aq.x * bt[q*4+0].w + aq.y * bt[q*4+1].w + aq.z * bt[q*4+2].w + aq.w * bt[q*4+3].w;
        }
        *(float4*)(out + (size_t)t * D + d0) = acc;
    }
}

extern "C" void kernel_launch(void* const* d_in, const int* in_sizes, int n_in,
                              void* d_out, int out_size, void* d_ws, size_t ws_size,
                              hipStream_t stream) {
    const int*   x      = (const int*)d_in[0];
    const int*   li     = (const int*)d_in[1];
    const float* base_w = (const float*)d_in[2];
    const float* lora_a = (const float*)d_in[3];
    const float* lora_b = (const float*)d_in[4];
    float*       out    = (float*)d_out;

    const int T = in_sizes[0];  // B*S = 4096

    float* bT     = (float*)d_ws;                        // NLORA*RANK*D floats (1 MB)
    int*   meta   = (int*)d_ws + NLORA * RANK * D;       // 64 ints
    int*   bucket = meta + 64;                           // T + NLORA*G ints (padded)
    int*   glora  = bucket + T + NLORA * G;              // T/G + NLORA ints

    prep_k<<<1 + (NLORA * RANK * D / 4) / BK_T, BK_T, 0, stream>>>(
        li, lora_b, meta, bucket, glora, bT, T);

    const int maxGroups = T / G + NLORA;
    dim3 grid(maxGroups, 2);
    lora_main_k<<<grid, 256, 0, stream>>>(x, bucket, glora, meta, base_w, lora_a, bT, out);
}

// Round 5
// 33.935 us; speedup vs baseline: 1.9307x; 1.0053x over previous
//
#include <hip/hip_runtime.h>

// VocabParallelEmbeddingWithLoRA — bucketed + transposed-B, 2-kernel pipeline.
// out[t, d] = base_weight[base_idx(t), d] + sum_r a[t,r] * lora_b[li[t], d, r]
//   a[t,:]      = lora_a[li[t], x[t], :]
//   base_idx(t) = x[t] + (x[t] >= ORG_VOCAB ? li[t]*EXTRA : 0)
//
// K1 (65 blocks x 1024 thr):
//   block 0      : bucketize (count -> prefix pad-to-G -> group map -> scatter)
//   blocks 1..64 : transpose lora_b [l][d][r] -> bT [l][r][d]
// K2 (dense grid (T/G + NLORA) x 4): block = 8 same-lora tokens x 512 d.
//   Thread owns 2 floats (float2). bT tile in registers (coalesced loads,
//   issued before the metadata barriers). All 8 base rows batch-prefetched
//   into registers -> 8 independent HBM gathers in flight per wave.

constexpr int ORG_VOCAB = 32000;
constexpr int EXTRA     = 256;
constexpr int RANK      = 16;
constexpr int D         = 2048;
constexpr int NLORA     = 8;
constexpr int G         = 8;       // tokens per main block
constexpr int DCHUNK    = 512;     // d-columns per main block
constexpr int BK_T      = 1024;    // k1 block size

// meta ints: [16..24) slot offsets, [24..32) group offsets, [40] total groups
__global__ __launch_bounds__(BK_T) void prep_k(
    const int*   __restrict__ li,
    const float* __restrict__ lora_b,   // [NLORA, D, RANK]
    int*   __restrict__ meta,
    int*   __restrict__ bucket,
    int*   __restrict__ glora,
    float* __restrict__ bT,             // [NLORA, RANK, D]
    int T)
{
    if (blockIdx.x != 0) {
        // ---- transpose slice: one float4 of bT per thread ----
        const int o4  = (blockIdx.x - 1) * BK_T + threadIdx.x;  // < 65536
        const int l   = o4 >> 13;           // RANK*D/4 = 8192 f4 per lora
        const int rem = o4 & 8191;
        const int r   = rem >> 9;           // D/4 = 512 f4 per rank-row
        const int d4  = rem & 511;
        const float* __restrict__ src = lora_b + ((size_t)(l * D + d4 * 4) * RANK + r);
        float4 v;
        v.x = src[0 * RANK];
        v.y = src[1 * RANK];
        v.z = src[2 * RANK];
        v.w = src[3 * RANK];
        ((float4*)bT)[o4] = v;
        return;
    }

    // ---- bucketize ----
    __shared__ int cnt[NLORA], cur[NLORA], soff[NLORA + 1], sgoff[NLORA + 1];
    const int tid  = threadIdx.x;
    const int lane = tid & 63;
    if (tid < NLORA) cnt[tid] = 0;
    __syncthreads();

    for (int t = tid; t < T; t += BK_T) {
        const int l = li[t];
        #pragma unroll
        for (int ll = 0; ll < NLORA; ++ll) {
            unsigned long long m = __ballot(l == ll);
            if (m != 0ull && lane == (__ffsll((long long)m) - 1))
                atomicAdd(&cnt[ll], __popcll(m));
        }
    }
    __syncthreads();

    if (tid == 0) {
        int s = 0, gs = 0;
        for (int l = 0; l < NLORA; ++l) {
            soff[l] = s; sgoff[l] = gs; cur[l] = s;
            const int ng = (cnt[l] + G - 1) / G;
            s += ng * G; gs += ng;
        }
        soff[NLORA] = s; sgoff[NLORA] = gs;
        #pragma unroll
        for (int l = 0; l < NLORA; ++l) { meta[16 + l] = soff[l]; meta[24 + l] = sgoff[l]; }
        meta[40] = gs;
    }
    __syncthreads();

    const int totalSlots  = soff[NLORA];
    const int totalGroups = sgoff[NLORA];
    for (int i = tid; i < totalSlots; i += BK_T) bucket[i] = -1;
    for (int g = tid; g < totalGroups; g += BK_T) {
        int l = 0;
        while (g >= sgoff[l + 1]) ++l;
        glora[g] = l;
    }
    __syncthreads();

    for (int t = tid; t < T; t += BK_T) {
        const int l = li[t];
        #pragma unroll
        for (int ll = 0; ll < NLORA; ++ll) {
            unsigned long long m = __ballot(l == ll);
            if (m == 0ull) continue;
            const int leader = __ffsll((long long)m) - 1;
            int base = 0;
            if (lane == leader) base = atomicAdd(&cur[ll], __popcll(m));
            base = __shfl(base, leader, 64);
            if (l == ll)
                bucket[base + __popcll(m & ((1ull << lane) - 1ull))] = t;
        }
    }
}

__global__ __launch_bounds__(256, 4) void lora_main_k(
    const int*   __restrict__ x,        // [T] token ids
    const int*   __restrict__ bucket,   // padded compact token positions
    const int*   __restrict__ glora,    // group -> lora
    const int*   __restrict__ meta,
    const float* __restrict__ base_w,   // [ORG_VOCAB + NLORA*EXTRA, D]
    const float* __restrict__ lora_a,   // [NLORA, ORG_VOCAB+EXTRA, RANK]
    const float* __restrict__ bT,       // [NLORA, RANK, D]
    float*       __restrict__ out)      // [T, D]
{
    const int g = blockIdx.x;
    if (g >= meta[40]) return;
    const int l     = glora[g];
    const int slot0 = meta[16 + l] + (g - meta[24 + l]) * G;
    const int d0    = blockIdx.y * DCHUNK + threadIdx.x * 2;

    // Register tile: bt[r] = bT[l][r][d0..d0+1] — coalesced float2 loads,
    // issued now so latency hides under the metadata/a-gather phase.
    float2 bt[RANK];
    const float* __restrict__ btl = bT + (size_t)l * (size_t)(RANK * D);
    #pragma unroll
    for (int r = 0; r < RANK; ++r)
        bt[r] = *(const float2*)(btl + (size_t)r * D + d0);

    __shared__ int   s_t[G];          // flat token position (or -1 pad)
    __shared__ int   s_bidx[G];       // base_weight row
    __shared__ float s_a[G][RANK];    // a-vectors

    if (threadIdx.x < G) {
        const int t   = bucket[slot0 + threadIdx.x];
        s_t[threadIdx.x] = t;
        const int tok = (t >= 0) ? x[t] : 0;
        s_bidx[threadIdx.x] = tok + (tok >= ORG_VOCAB ? l * EXTRA : 0);
        s_a[threadIdx.x][0] = __int_as_float(tok);   // stash for a-gather
    }
    __syncthreads();
    int tokid = 0;
    if (threadIdx.x < G * RANK) tokid = __float_as_int(s_a[threadIdx.x >> 4][0]);
    __syncthreads();
    if (threadIdx.x < G * RANK) {                    // 128 threads
        const int i = threadIdx.x >> 4;
        const int r = threadIdx.x & 15;
        s_a[i][r] = (s_t[i] >= 0)
            ? lora_a[((size_t)l * (ORG_VOCAB + EXTRA) + (size_t)tokid) * RANK + r]
            : 0.0f;
    }
    __syncthreads();

    // Batch-prefetch all G base rows: 8 independent HBM gathers in flight.
    float2 base[G];
    #pragma unroll
    for (int i = 0; i < G; ++i)
        base[i] = *(const float2*)(base_w + (size_t)s_bidx[i] * D + d0);

    #pragma unroll
    for (int i = 0; i < G; ++i) {
        const int t = s_t[i];               // uniform across block
        float2 acc = base[i];
        #pragma unroll
        for (int q = 0; q < 4; ++q) {
            const float4 aq = *(const float4*)(&s_a[i][q * 4]);
            acc.x += aq.x * bt[q*4+0].x + aq.y * bt[q*4+1].x + aq.z * bt[q*4+2].x + aq.w * bt[q*4+3].x;
            acc.y += aq.x * bt[q*4+0].y + aq.y * bt[q*4+1].y + aq.z * bt[q*4+2].y + aq.w * bt[q*4+3].y;
        }
        if (t >= 0)
            *(float2*)(out + (size_t)t * D + d0) = acc;
    }
}

extern "C" void kernel_launch(void* const* d_in, const int* in_sizes, int n_in,
                              void* d_out, int out_size, void* d_ws, size_t ws_size,
                              hipStream_t stream) {
    const int*   x      = (const int*)d_in[0];
    const int*   li     = (const int*)d_in[1];
    const float* base_w = (const float*)d_in[2];
    const float* lora_a = (const float*)d_in[3];
    const float* lora_b = (const float*)d_in[4];
    float*       out    = (float*)d_out;

    const int T = in_sizes[0];  // B*S = 4096

    float* bT     = (float*)d_ws;                        // NLORA*RANK*D floats (1 MB)
    int*   meta   = (int*)d_ws + NLORA * RANK * D;       // 64 ints
    int*   bucket = meta + 64;                           // T + NLORA*G ints (padded)
    int*   glora  = bucket + T + NLORA * G;              // T/G + NLORA ints

    prep_k<<<1 + (NLORA * RANK * D / 4) / BK_T, BK_T, 0, stream>>>(
        li, lora_b, meta, bucket, glora, bT, T);

    const int maxGroups = T / G + NLORA;
    dim3 grid(maxGroups, D / DCHUNK);
    lora_main_k<<<grid, 256, 0, stream>>>(x, bucket, glora, meta, base_w, lora_a, bT, out);
}

// Round 7
// 21.354 us; speedup vs baseline: 3.0682x; 1.5891x over previous
//
#include <hip/hip_runtime.h>

// VocabParallelEmbeddingWithLoRA — SINGLE ordinary kernel, no inter-block deps.
// out[t, d] = base_weight[base_idx(t), d] + sum_r a[t,r] * lora_b[li[t], d, r]
//   a[t,:]      = lora_a[li[t], x[t], :]
//   base_idx(t) = x[t] + (x[t] >= ORG_VOCAB ? li[t]*EXTRA : 0)
//
// Block = (lora l, token stripe of 128, d-chunk of 512). 8*32*4 = 1024 blocks
// = 4/CU co-resident. Each block stages its 32 KB lora_b slice contiguously
// into LDS ([512][17] pad -> 2-way-free reads), finds stripe tokens with
// li[t]==l via ballots, then per token: prefetch base row chunk, rank-16 FMA
// from registers, store. Every (t,d) written by exactly one block.

constexpr int ORG_VOCAB = 32000;
constexpr int EXTRA     = 256;
constexpr int RANK      = 16;
constexpr int D         = 2048;
constexpr int NLORA     = 8;
constexpr int SPLIT     = 32;              // token stripes
constexpr int SLEN      = 128;             // tokens per stripe (T=4096)
constexpr int DCHUNK    = 512;             // d-columns per block
constexpr int NY        = D / DCHUNK;      // 4
constexpr int BLK       = 256;

__global__ __launch_bounds__(BLK, 4) void lora_fused_k(
    const int*   __restrict__ x,        // [T] token ids
    const int*   __restrict__ li,       // [T] lora indices
    const float* __restrict__ base_w,   // [ORG_VOCAB + NLORA*EXTRA, D]
    const float* __restrict__ lora_a,   // [NLORA, ORG_VOCAB+EXTRA, RANK]
    const float* __restrict__ lora_b,   // [NLORA, D, RANK]
    float*       __restrict__ out,      // [T, D]
    int T)
{
    const int l      = blockIdx.x >> 5;            // / SPLIT
    const int stripe = blockIdx.x & (SPLIT - 1);
    const int y      = blockIdx.y;
    const int tid    = threadIdx.x;
    const int t0     = stripe * SLEN;

    __shared__ float sb[DCHUNK][RANK + 1];         // 34.8 KB, 2-way-free reads
    __shared__ int   s_tok[SLEN], s_bidx[SLEN], s_li[SLEN];
    __shared__ int   s_mt[SLEN];
    __shared__ int   s_nm;
    __shared__ float s_ab[2][8][RANK];             // double-buffered a-vectors

    // ---- stage lora_b slice: 32 KB contiguous, fully coalesced ----
    const float* __restrict__ bsrc =
        lora_b + ((size_t)l * D + (size_t)y * DCHUNK) * RANK;
    #pragma unroll
    for (int k = 0; k < (DCHUNK * RANK) / (BLK * 4); ++k) {   // 8 iters
        const int g4 = k * BLK + tid;              // float4 index in slice
        const float4 v = ((const float4*)bsrc)[g4];
        const int d  = g4 >> 2;                    // 4 float4 per d-row
        const int r4 = (g4 & 3) * 4;
        sb[d][r4 + 0] = v.x; sb[d][r4 + 1] = v.y;
        sb[d][r4 + 2] = v.z; sb[d][r4 + 3] = v.w;
    }

    // ---- stage stripe metadata ----
    if (tid < SLEN) {
        const int t = t0 + tid;
        int lt = -1, tok = 0;
        if (t < T) { lt = li[t]; tok = x[t]; }
        s_li[tid]   = lt;
        s_tok[tid]  = tok;
        s_bidx[tid] = tok + (tok >= ORG_VOCAB ? lt * EXTRA : 0);
    }
    __syncthreads();

    // ---- match list: stripe positions with li == l (wave 0, ordered) ----
    if (tid < 64) {
        const unsigned long long below = (tid == 63) ? 0x7fffffffffffffffull
                                                     : ((1ull << tid) - 1ull);
        const bool f0 = (s_li[tid] == l);
        const unsigned long long m0 = __ballot(f0);
        const bool f1 = (s_li[tid + 64] == l);
        const unsigned long long m1 = __ballot(f1);
        const int c0 = __popcll(m0);
        if (f0) s_mt[__popcll(m0 & below)] = tid;
        if (f1) s_mt[c0 + __popcll(m1 & below)] = tid + 64;
        if (tid == 0) s_nm = c0 + __popcll(m1);
    }

    // bt registers from LDS (needs sb ready; lane stride 17 -> 2-way free)
    float bt0[RANK], bt1[RANK];
    __syncthreads();
    #pragma unroll
    for (int r = 0; r < RANK; ++r) {
        bt0[r] = sb[tid][r];
        bt1[r] = sb[tid + 256][r];
    }

    const int nm = s_nm;
    const size_t d0 = (size_t)y * DCHUNK + tid;    // owns d0 and d0+256

    int par = 0;
    for (int mb = 0; mb < nm; mb += 8, par ^= 1) {
        const int nb = (nm - mb < 8) ? (nm - mb) : 8;

        // a-vectors for this batch (gathered by 128 threads)
        {
            const int i = tid >> 4, r = tid & 15;
            if (tid < 128 && i < nb) {
                const int k = s_mt[mb + i];
                s_ab[par][i][r] =
                    lora_a[((size_t)l * (ORG_VOCAB + EXTRA) + (size_t)s_tok[k]) * RANK + r];
            }
        }

        // prefetch base rows: 16 independent loads in flight
        float b0[8], b1[8];
        #pragma unroll
        for (int i = 0; i < 8; ++i) {
            const int ii = (i < nb) ? i : (nb - 1);
            const int k  = s_mt[mb + ii];
            const float* __restrict__ br = base_w + (size_t)s_bidx[k] * D + d0;
            b0[i] = br[0];
            b1[i] = br[256];
        }

        __syncthreads();   // s_ab[par] ready (also drains prefetch loads)

        #pragma unroll
        for (int i = 0; i < 8; ++i) {
            if (i >= nb) break;
            const int k = s_mt[mb + i];
            const float4 a0 = *(const float4*)&s_ab[par][i][0];
            const float4 a1 = *(const float4*)&s_ab[par][i][4];
            const float4 a2 = *(const float4*)&s_ab[par][i][8];
            const float4 a3 = *(const float4*)&s_ab[par][i][12];
            float acc0 = b0[i], acc1 = b1[i];
            acc0 += a0.x*bt0[0]  + a0.y*bt0[1]  + a0.z*bt0[2]  + a0.w*bt0[3]
                  + a1.x*bt0[4]  + a1.y*bt0[5]  + a1.z*bt0[6]  + a1.w*bt0[7]
                  + a2.x*bt0[8]  + a2.y*bt0[9]  + a2.z*bt0[10] + a2.w*bt0[11]
                  + a3.x*bt0[12] + a3.y*bt0[13] + a3.z*bt0[14] + a3.w*bt0[15];
            acc1 += a0.x*bt1[0]  + a0.y*bt1[1]  + a0.z*bt1[2]  + a0.w*bt1[3]
                  + a1.x*bt1[4]  + a1.y*bt1[5]  + a1.z*bt1[6]  + a1.w*bt1[7]
                  + a2.x*bt1[8]  + a2.y*bt1[9]  + a2.z*bt1[10] + a2.w*bt1[11]
                  + a3.x*bt1[12] + a3.y*bt1[13] + a3.z*bt1[14] + a3.w*bt1[15];
            const int t = t0 + k;
            float* __restrict__ orow = out + (size_t)t * D + d0;
            orow[0]   = acc0;
            orow[256] = acc1;
        }
    }
}

extern "C" void kernel_launch(void* const* d_in, const int* in_sizes, int n_in,
                              void* d_out, int out_size, void* d_ws, size_t ws_size,
                              hipStream_t stream) {
    const int*   x      = (const int*)d_in[0];
    const int*   li     = (const int*)d_in[1];
    const float* base_w = (const float*)d_in[2];
    const float* lora_a = (const float*)d_in[3];
    const float* lora_b = (const float*)d_in[4];
    float*       out    = (float*)d_out;

    int T = in_sizes[0];  // B*S = 4096

    dim3 grid(NLORA * SPLIT, NY);     // 256 x 4 = 1024 blocks = 4/CU
    lora_fused_k<<<grid, BLK, 0, stream>>>(x, li, base_w, lora_a, lora_b, out, T);
}

// Round 8
// 20.974 us; speedup vs baseline: 3.1239x; 1.0182x over previous
//
#include <hip/hip_runtime.h>

// VocabParallelEmbeddingWithLoRA — single kernel, no inter-block deps.
// out[t, d] = base_weight[base_idx(t), d] + sum_r a[t,r] * lora_b[li[t], d, r]
//   a[t,:]      = lora_a[li[t], x[t], :]
//   base_idx(t) = x[t] + (x[t] >= ORG_VOCAB ? li[t]*EXTRA : 0)
//
// Block = (lora l, stripe of 64 tokens, d-chunk of 512). 8*64*4 = 2048 blocks
// (2 rounds of ~4/CU -> dispatcher backfill balances ragged nm). Per block:
// stage 32 KB lora_b slice into LDS ([512][17] pad, 2-way-free), build match
// list with one ballot, gather ALL a-vectors up-front, then a BARRIER-FREE
// main loop: double-buffered base-row prefetch (8 independent float2 loads
// in flight) overlapping rank-16 FMAs. float2 everywhere (512 B/wave-instr).

constexpr int ORG_VOCAB = 32000;
constexpr int EXTRA     = 256;
constexpr int RANK      = 16;
constexpr int D         = 2048;
constexpr int NLORA     = 8;
constexpr int SPLIT     = 64;              // token stripes
constexpr int SLEN      = 64;              // tokens per stripe (T=4096)
constexpr int DCHUNK    = 512;             // d-columns per block
constexpr int NY        = D / DCHUNK;      // 4
constexpr int BLK       = 256;

__device__ __forceinline__ void load_batch(
    float2* buf, int mb, int nm,
    const int* s_mt, const int* s_bidx,
    const float* __restrict__ base_w, int d0)
{
    #pragma unroll
    for (int i = 0; i < 8; ++i) {
        const int ii = (mb + i < nm) ? (mb + i) : (nm - 1);
        const int k  = s_mt[ii];
        buf[i] = *(const float2*)(base_w + (size_t)s_bidx[k] * D + d0);
    }
}

__device__ __forceinline__ void proc_batch(
    const float2* buf, int mb, int nm, int t0,
    const int* s_mt, const float (*s_a)[RANK],
    const float* bt0, const float* bt1,
    float* __restrict__ out, int d0)
{
    #pragma unroll
    for (int i = 0; i < 8; ++i) {
        if (mb + i >= nm) break;
        const int k  = s_mt[mb + i];
        const float4 a0 = *(const float4*)&s_a[mb + i][0];
        const float4 a1 = *(const float4*)&s_a[mb + i][4];
        const float4 a2 = *(const float4*)&s_a[mb + i][8];
        const float4 a3 = *(const float4*)&s_a[mb + i][12];
        float2 acc = buf[i];
        acc.x += a0.x*bt0[0]  + a0.y*bt0[1]  + a0.z*bt0[2]  + a0.w*bt0[3]
               + a1.x*bt0[4]  + a1.y*bt0[5]  + a1.z*bt0[6]  + a1.w*bt0[7]
               + a2.x*bt0[8]  + a2.y*bt0[9]  + a2.z*bt0[10] + a2.w*bt0[11]
               + a3.x*bt0[12] + a3.y*bt0[13] + a3.z*bt0[14] + a3.w*bt0[15];
        acc.y += a0.x*bt1[0]  + a0.y*bt1[1]  + a0.z*bt1[2]  + a0.w*bt1[3]
               + a1.x*bt1[4]  + a1.y*bt1[5]  + a1.z*bt1[6]  + a1.w*bt1[7]
               + a2.x*bt1[8]  + a2.y*bt1[9]  + a2.z*bt1[10] + a2.w*bt1[11]
               + a3.x*bt1[12] + a3.y*bt1[13] + a3.z*bt1[14] + a3.w*bt1[15];
        *(float2*)(out + (size_t)(t0 + k) * D + d0) = acc;
    }
}

__global__ __launch_bounds__(BLK, 4) void lora_fused_k(
    const int*   __restrict__ x,        // [T] token ids
    const int*   __restrict__ li,       // [T] lora indices
    const float* __restrict__ base_w,   // [ORG_VOCAB + NLORA*EXTRA, D]
    const float* __restrict__ lora_a,   // [NLORA, ORG_VOCAB+EXTRA, RANK]
    const float* __restrict__ lora_b,   // [NLORA, D, RANK]
    float*       __restrict__ out,      // [T, D]
    int T)
{
    const int l      = blockIdx.x >> 6;            // / SPLIT
    const int stripe = blockIdx.x & (SPLIT - 1);
    const int y      = blockIdx.y;
    const int tid    = threadIdx.x;
    const int t0     = stripe * SLEN;

    __shared__ float sb[DCHUNK][RANK + 1];         // 34.8 KB, 2-way-free reads
    __shared__ int   s_tok[SLEN], s_bidx[SLEN], s_mt[SLEN];
    __shared__ int   s_nm;
    __shared__ float s_a[SLEN][RANK];              // 4 KB

    // ---- stage lora_b slice: 32 KB contiguous, fully coalesced ----
    const float* __restrict__ bsrc =
        lora_b + ((size_t)l * D + (size_t)y * DCHUNK) * RANK;
    #pragma unroll
    for (int k = 0; k < (DCHUNK * RANK) / (BLK * 4); ++k) {   // 8 iters
        const int g4 = k * BLK + tid;              // float4 index in slice
        const float4 v = ((const float4*)bsrc)[g4];
        const int d  = g4 >> 2;
        const int r4 = (g4 & 3) * 4;
        sb[d][r4 + 0] = v.x; sb[d][r4 + 1] = v.y;
        sb[d][r4 + 2] = v.z; sb[d][r4 + 3] = v.w;
    }

    // ---- stripe metadata + match list (wave 0 covers the 64-token stripe) ----
    if (tid < SLEN) {
        const int t   = t0 + tid;
        const int lt  = (t < T) ? li[t] : -1;
        const int tok = (t < T) ? x[t] : 0;
        s_tok[tid]  = tok;
        s_bidx[tid] = tok + (tok >= ORG_VOCAB ? lt * EXTRA : 0);
        const bool f = (lt == l);
        const unsigned long long m = __ballot(f);
        const unsigned long long below = (1ull << tid) - 1ull;
        if (f) s_mt[__popcll(m & below)] = tid;
        if (tid == 0) s_nm = __popcll(m);
    }
    __syncthreads();

    const int nm = s_nm;
    if (nm == 0) return;

    // bt registers from LDS (rows 2*tid, 2*tid+1; pad-17 -> 2-way free)
    float bt0[RANK], bt1[RANK];
    #pragma unroll
    for (int r = 0; r < RANK; ++r) {
        bt0[r] = sb[2 * tid][r];
        bt1[r] = sb[2 * tid + 1][r];
    }

    // ---- gather ALL a-vectors up-front ----
    for (int j = tid; j < nm * RANK; j += BLK) {
        const int i = j >> 4, r = j & 15;
        s_a[i][r] = lora_a[((size_t)l * (ORG_VOCAB + EXTRA)
                            + (size_t)s_tok[s_mt[i]]) * RANK + r];
    }
    __syncthreads();

    // ---- barrier-free main loop, double-buffered prefetch ----
    const int d0 = y * DCHUNK + tid * 2;
    float2 bufA[8], bufB[8];

    load_batch(bufA, 0, nm, s_mt, s_bidx, base_w, d0);
    int mb = 0;
    while (true) {
        if (mb + 8 < nm) load_batch(bufB, mb + 8, nm, s_mt, s_bidx, base_w, d0);
        proc_batch(bufA, mb, nm, t0, s_mt, s_a, bt0, bt1, out, d0);
        mb += 8;
        if (mb >= nm) break;
        if (mb + 8 < nm) load_batch(bufA, mb + 8, nm, s_mt, s_bidx, base_w, d0);
        proc_batch(bufB, mb, nm, t0, s_mt, s_a, bt0, bt1, out, d0);
        mb += 8;
        if (mb >= nm) break;
    }
}

extern "C" void kernel_launch(void* const* d_in, const int* in_sizes, int n_in,
                              void* d_out, int out_size, void* d_ws, size_t ws_size,
                              hipStream_t stream) {
    const int*   x      = (const int*)d_in[0];
    const int*   li     = (const int*)d_in[1];
    const float* base_w = (const float*)d_in[2];
    const float* lora_a = (const float*)d_in[3];
    const float* lora_b = (const float*)d_in[4];
    float*       out    = (float*)d_out;

    int T = in_sizes[0];  // B*S = 4096

    dim3 grid(NLORA * SPLIT, NY);     // 512 x 4 = 2048 blocks
    lora_fused_k<<<grid, BLK, 0, stream>>>(x, li, base_w, lora_a, lora_b, out, T);
}